// Round 2
// baseline (109.995 us; speedup 1.0000x reference)
//
#include <hip/hip_runtime.h>

// VQ nearest-neighbor via f16-split MFMA. N=65536 queries, DIM=64, K=1024.
// v = dot(z,c) - csq[k]/2; argmax_k v  ==  argmin_k ||z-c||^2.
// 2-term f16 split (absmax=0 verified): dot ~= zh.ch + 2^-11(zh.cl'+zl'.ch).
//
// Round-7 structure (fixes round 6's occupancy bound):
//  * Round 6 ran 2 waves/SIMD (VGPR ~150 > 128 cliff) -> every L2/LDS stall
//    exposed; vq ~40 us vs 12.4 us MFMA floor (MfmaUtil ~30%).
//  * Now: block = 64 queries x 4 waves = 4 K-QUARTERS (256 codes each).
//    Per-wave B bytes halve (64 KB); wave count doubles (4096) -> total L2
//    B-traffic unchanged (268 MB). Grid 1024 = 4 blocks/CU = 4 waves/SIMD.
//  * VGPR diet to fit <=128 (the occupancy cliff): no B-prefetch regs (TLP
//    from 4 waves/SIMD covers the ~200 cy L2 latency), and the per-slot
//    argmax index is a byte-packed tile id (bestt[qt], one byte per r;
//    k = kh*256 + t*16 + m reconstructed post-loop). 64 A + 16 best +
//    4 bestt + ~16 B transient + ~16 accum + addr ~ 124.
//  * __launch_bounds__(256, 4) enforces the 128-VGPR cap.
//  * Exact tie-break preserved: strict > with t ascending per lane keeps
//    lowest k; kh-ascending combine keeps lowest K-quarter on ties.

typedef _Float16 half8 __attribute__((ext_vector_type(8)));
typedef float float4v __attribute__((ext_vector_type(4)));

constexpr int KCODES = 1024;
constexpr int DIM = 64;
constexpr int BLOCK = 256;

// d_ws layout
constexpr size_t WS_CSQN = 0;      // 1024 f32 (-csq/2)            = 4 KB
constexpr size_t WS_CBF = 4096;    // fragment-ordered split cb f16 = 256 KB

// Fragment-ordered split codebook:
// cbf[((T*2+kt)*2+hl)*512 + lane*8 + j], lane = quad*16+m, code = T*16+m,
// dim = kt*32 + quad*8 + j. hl=0: f16 high part; hl=1: residual * 2^11.
//
// Thread g handles (code k = g>>3, kt = (g>>2)&1, quad = g&3): loads 8
// CONSECUTIVE floats (coalesced), writes one h8 + one l8 fragment, reduces
// csq across the 8 sub-threads via shfl (xor 1/2/4 stays in-wave).
__global__ __launch_bounds__(BLOCK) void prep_kernel(
    const float* __restrict__ cb, _Float16* __restrict__ cbf,
    float* __restrict__ csqn) {
  const int g = blockIdx.x * BLOCK + threadIdx.x;  // grid 32 x 256 = 8192
  const int k = g >> 3, sub = g & 7;
  const int kt = sub >> 2, quad = sub & 3;
  const int t = k >> 4, m = k & 15;

  const float* src = cb + (size_t)k * DIM + kt * 32 + quad * 8;
  const float4 p0 = ((const float4*)src)[0];
  const float4 p1 = ((const float4*)src)[1];
  const float x[8] = {p0.x, p0.y, p0.z, p0.w, p1.x, p1.y, p1.z, p1.w};

  half8 h8, l8;
  float s = 0.f;
#pragma unroll
  for (int j = 0; j < 8; ++j) {
    s = fmaf(x[j], x[j], s);
    const _Float16 h = (_Float16)x[j];
    h8[j] = h;
    l8[j] = (_Float16)((x[j] - (float)h) * 2048.0f);
  }
  s += __shfl_xor(s, 1);
  s += __shfl_xor(s, 2);
  s += __shfl_xor(s, 4);
  if (sub == 0) csqn[k] = -0.5f * s;

  const int lane8 = quad * 16 + m;
  _Float16* dst = cbf + (size_t)((t * 2 + kt) * 2) * 512 + lane8 * 8;
  *(half8*)(dst) = h8;        // hl = 0
  *(half8*)(dst + 512) = l8;  // hl = 1
}

// Block = 256 thr = 4 waves = 1 query-group (64 q) x 4 K-quarters.
__global__ __launch_bounds__(BLOCK, 4) void vq_mfma(
    const float* __restrict__ z, const float4* __restrict__ cb4,
    const _Float16* __restrict__ cbf, const float* __restrict__ csqn_g,
    float4* __restrict__ out4) {
  __shared__ float scsqn[KCODES];
  __shared__ float rv[4][64];
  __shared__ int rk[4][64];
  __shared__ int sidx[64];

  const int tid = threadIdx.x;
  const int lane = tid & 63;
  const int kh = tid >> 6;    // wave = K quarter (256 codes)
  const int m = lane & 15;
  const int quad = lane >> 4;

  ((float4*)scsqn)[tid] = ((const float4*)csqn_g)[tid];

  // A-fragments: 4 qtiles x 2 ktiles, h + l. A[m][k=quad*8+j].
  const int qbase = blockIdx.x * 64;
  half8 ah[4][2], al[4][2];
#pragma unroll
  for (int qt = 0; qt < 4; ++qt) {
    const float* zr = z + (size_t)(qbase + qt * 16 + m) * DIM + quad * 8;
#pragma unroll
    for (int kt = 0; kt < 2; ++kt) {
      const float4 p0 = ((const float4*)(zr + kt * 32))[0];
      const float4 p1 = ((const float4*)(zr + kt * 32))[1];
      const float zf[8] = {p0.x, p0.y, p0.z, p0.w, p1.x, p1.y, p1.z, p1.w};
#pragma unroll
      for (int j = 0; j < 8; ++j) {
        const _Float16 h = (_Float16)zf[j];
        ah[qt][kt][j] = h;
        al[qt][kt][j] = (_Float16)((zf[j] - (float)h) * 2048.0f);
      }
    }
  }

  __syncthreads();  // scsqn visible

  const float4v zvec = {0.f, 0.f, 0.f, 0.f};
  float best[4][4];
  unsigned bestt[4];  // byte r of bestt[qt] = winning tile id for slot r
#pragma unroll
  for (int qt = 0; qt < 4; ++qt) {
    bestt[qt] = 0u;
#pragma unroll
    for (int r = 0; r < 4; ++r) best[qt][r] = -3.402823466e38f;
  }

  // B base: this wave's K-quarter, fragment-ordered -> contiguous 1 KB loads.
  const _Float16* bbase = cbf + (size_t)kh * 32768 + lane * 8;

#pragma unroll 1
  for (int t = 0; t < 16; ++t) {
    const _Float16* pt = bbase + (size_t)t * 2048;
    const half8 bh0 = *(const half8*)(pt);          // kt0, h
    const half8 bl0 = *(const half8*)(pt + 512);    // kt0, l
    const half8 bh1 = *(const half8*)(pt + 1024);   // kt1, h
    const half8 bl1 = *(const half8*)(pt + 1536);   // kt1, l

    const float c = scsqn[kh * 256 + t * 16 + m];   // this lane's code column
    const float4v cvec = {c, c, c, c};

    __builtin_amdgcn_s_setprio(1);
#pragma unroll
    for (int qt = 0; qt < 4; ++qt) {
      float4v am = __builtin_amdgcn_mfma_f32_16x16x32_f16(ah[qt][0], bh0, cvec, 0, 0, 0);
      am = __builtin_amdgcn_mfma_f32_16x16x32_f16(ah[qt][1], bh1, am, 0, 0, 0);
      float4v ax = __builtin_amdgcn_mfma_f32_16x16x32_f16(ah[qt][0], bl0, zvec, 0, 0, 0);
      ax = __builtin_amdgcn_mfma_f32_16x16x32_f16(ah[qt][1], bl1, ax, 0, 0, 0);
      ax = __builtin_amdgcn_mfma_f32_16x16x32_f16(al[qt][0], bh0, ax, 0, 0, 0);
      ax = __builtin_amdgcn_mfma_f32_16x16x32_f16(al[qt][1], bh1, ax, 0, 0, 0);
#pragma unroll
      for (int r = 0; r < 4; ++r) {
        const float v = fmaf(4.8828125e-4f, ax[r], am[r]);  // 2^-11
        // k ascending in t per lane: strict > keeps lowest-k maximum.
        const bool gt = v > best[qt][r];
        best[qt][r] = gt ? v : best[qt][r];
        const unsigned cand =
            (bestt[qt] & ~(0xFFu << (8 * r))) | ((unsigned)t << (8 * r));
        bestt[qt] = gt ? cand : bestt[qt];
      }
    }
    __builtin_amdgcn_s_setprio(0);
  }

  // Cross-lane argmax over the 16 cols (m) in each quad; ties -> lower k.
#pragma unroll
  for (int qt = 0; qt < 4; ++qt)
#pragma unroll
    for (int r = 0; r < 4; ++r) {
      float b = best[qt][r];
      int bk = kh * 256 + (int)((bestt[qt] >> (8 * r)) & 0xFFu) * 16 + m;
#pragma unroll
      for (int s = 1; s < 16; s <<= 1) {
        const float ob = __shfl_xor(b, s);
        const int obk = __shfl_xor(bk, s);
        if (ob > b || (ob == b && obk < bk)) { b = ob; bk = obk; }
      }
      if (m == 0) {
        const int qb = qt * 16 + quad * 4 + r;  // row = quad*4+r
        rv[kh][qb] = b;
        rk[kh][qb] = bk;
      }
    }
  __syncthreads();

  // Combine K-quarters (strict >: ties -> lower kh = lower k).
  if (tid < 64) {
    float v = rv[0][tid];
    int bk = rk[0][tid];
#pragma unroll
    for (int h = 1; h < 4; ++h) {
      const float vh = rv[h][tid];
      const int kh2 = rk[h][tid];
      if (vh > v) { v = vh; bk = kh2; }
    }
    sidx[tid] = bk;
  }
  __syncthreads();

  // Gather winning fp32 codebook rows; coalesced float4 writes.
  const size_t obase = (size_t)blockIdx.x * 64 * (DIM / 4);
#pragma unroll
  for (int f0 = 0; f0 < 64 * (DIM / 4); f0 += BLOCK) {
    const int f = f0 + tid;
    const int q = f >> 4, e = f & 15;
    out4[obase + f] = cb4[(size_t)sidx[q] * (DIM / 4) + e];
  }
}

extern "C" void kernel_launch(void* const* d_in, const int* in_sizes, int n_in,
                              void* d_out, int out_size, void* d_ws, size_t ws_size,
                              hipStream_t stream) {
  const float* z = (const float*)d_in[0];
  const float* cb = (const float*)d_in[1];
  char* ws = (char*)d_ws;
  float* csqn = (float*)(ws + WS_CSQN);
  _Float16* cbf = (_Float16*)(ws + WS_CBF);

  const int nq = in_sizes[0] / DIM;  // 65536
  prep_kernel<<<(KCODES * 8) / BLOCK, BLOCK, 0, stream>>>(cb, cbf, csqn);
  vq_mfma<<<nq / 64, BLOCK, 0, stream>>>(z, (const float4*)cb, cbf, csqn,
                                         (float4*)d_out);
}